// Round 7
// baseline (96.182 us; speedup 1.0000x reference)
//
#include <hip/hip_runtime.h>

#define BB 4
#define NN 2048
#define DD 256
#define NPAIR 16
#define GCX 40                    // 640/16 cells in x
#define GCY 30                    // 480/16 cells in y
#define NCELL (GCX * GCY)         // 1200
#define CSTRIDE 1216              // starts row stride (ints)
#define HCAP 4096                 // per-pair hit list capacity (mean ~2.8K, +25 sigma)
#define WQ_CAP 256                // per-wave match queue (lambda ~88, +10 sigma)
#define MBLK (NPAIR * 8)          // 128 match blocks: pair x tile of 256 src
#define CBLK (NPAIR * 128)        // 2048 cos blocks: pair x chunk of 32 hits

// ws layout (bytes) — ~800 KB of the 256 MiB workspace
#define OFF_BX 131072                      // float2[16][2048] = 262144
#define OFF_BM (OFF_BX + 262144)           // int[16][2048]    = 131072
#define OFF_HC (OFF_BM + 131072)           // uint[16] counters (4 KB reserved)
#define OFF_HL (OFF_HC + 4096)             // uint[16][4096] hit lists = 262144
#define OFF_PS (OFF_HL + 262144)           // float[2048] partials

__device__ __forceinline__ int cell_clamp(int v, int hi) {
    return v < 0 ? 0 : (v > hi ? hi : v);
}

// Kernel 1 (16 blocks): per-pair counting sort of dst points into 16px
// cells — verbatim the absmax-0.0-verified round-5 build — plus zeroing
// this pair's hit counter (stream order makes it visible to match).
__global__ __launch_bounds__(256) void build_kernel(const float* __restrict__ pts_dst,
                                                    const int* __restrict__ hptr,
                                                    const int* __restrict__ wptr,
                                                    int* __restrict__ starts,
                                                    float2* __restrict__ bx,
                                                    int* __restrict__ bm,
                                                    unsigned int* __restrict__ hitcnt) {
    __shared__ int cnt[NCELL];                           // counts -> scatter cursors
    __shared__ int tsum[256];
    const int pair = blockIdx.x;
    const float sx = ((float)(*wptr) - 1.0f) * 0.5f;
    const float sy = ((float)(*hptr) - 1.0f) * 0.5f;
    if (threadIdx.x == 0) hitcnt[pair] = 0u;

    for (int t = threadIdx.x; t < NCELL; t += 256) cnt[t] = 0;
    __syncthreads();

    // pass 1: denorm + count (8 points/thread, coalesced)
    const float2* pd = (const float2*)(pts_dst + (size_t)pair * NN * 2);
    float qx[8], qy[8]; int qc[8];
#pragma unroll
    for (int k = 0; k < 8; ++k) {
        const float2 r = pd[threadIdx.x + k * 256];
        qx[k] = fmaf(r.x, sx, sx);                       // exact same denorm form
        qy[k] = fmaf(r.y, sy, sy);
        const int cx = cell_clamp((int)(qx[k] * 0.0625f), GCX - 1);
        const int cy = cell_clamp((int)(qy[k] * 0.0625f), GCY - 1);
        qc[k] = cx + GCX * cy;
        atomicAdd(&cnt[qc[k]], 1);
    }
    __syncthreads();

    // exclusive prefix over 1200 cells: 5 cells/thread + Hillis-Steele
    const int base = threadIdx.x * 5;
    int loc[5]; int s = 0;
#pragma unroll
    for (int k = 0; k < 5; ++k) {
        const int c = base + k;
        const int v = (c < NCELL) ? cnt[c] : 0;
        loc[k] = s; s += v;
    }
    tsum[threadIdx.x] = s;
    __syncthreads();
    for (int off = 1; off < 256; off <<= 1) {
        const int v = (threadIdx.x >= off) ? tsum[threadIdx.x - off] : 0;
        __syncthreads();
        tsum[threadIdx.x] += v;
        __syncthreads();
    }
    const int tbase = tsum[threadIdx.x] - s;             // exclusive thread base
    int* gst = starts + pair * CSTRIDE;
#pragma unroll
    for (int k = 0; k < 5; ++k) {
        const int c = base + k;
        if (c < NCELL) {
            const int st = tbase + loc[k];
            gst[c] = st;                                 // global cell starts
            cnt[c] = st;                                 // LDS scatter cursor
        }
    }
    if (threadIdx.x == 0) gst[NCELL] = NN;               // sentinel end
    __syncthreads();

    // pass 2: scatter denormed points + original m index
    float2* gbx = bx + (size_t)pair * NN;
    int*    gbm = bm + (size_t)pair * NN;
#pragma unroll
    for (int k = 0; k < 8; ++k) {
        const int pos = atomicAdd(&cnt[qc[k]], 1);       // pos < NN by construction
        gbx[pos] = make_float2(qx[k], qy[k]);
        gbm[pos] = threadIdx.x + k * 256;
    }
}

// Kernel 2 (128 blocks): block = (pair, src-tile of 256), ONE thread per
// src point walking its full 3x3 neighborhood as 3 contiguous cell-row
// ranges (cells >=2 apart are >8px away, exact on denormed floats =>
// candidate superset; d2 test bit-identical => identical hit set).
// Hits -> per-wave LDS queue, flushed with ONE atomicAdd per wave to the
// pair's global hit list; count is exact even if the list clamps.
__global__ __launch_bounds__(256) void match_kernel(const float* __restrict__ pts_src,
                                                    const int* __restrict__ hptr,
                                                    const int* __restrict__ wptr,
                                                    const int* __restrict__ starts,
                                                    const float2* __restrict__ bx,
                                                    const int* __restrict__ bm,
                                                    unsigned int* __restrict__ hitcnt,
                                                    unsigned int* __restrict__ hitlist) {
    __shared__ unsigned int wq[4][WQ_CAP];
    __shared__ unsigned int wqc[4];
    const int pair = blockIdx.x & 15;                    // pair&7 == XCD under round-robin
    const int tile = blockIdx.x >> 4;                    // 0..7
    const int i = pair >> 2;
    const float sx = ((float)(*wptr) - 1.0f) * 0.5f;
    const float sy = ((float)(*hptr) - 1.0f) * 0.5f;

    const int wave = threadIdx.x >> 6;
    const int lane = threadIdx.x & 63;
    if (lane == 0) wqc[wave] = 0u;                       // same-wave order: no barrier

    const int nloc = threadIdx.x;                        // src point of this thread
    const float2 r = ((const float2*)pts_src)[(size_t)i * NN + tile * 256 + nloc];
    const float px = fmaf(r.x, sx, sx);
    const float py = fmaf(r.y, sy, sy);
    const int cxs = cell_clamp((int)(px * 0.0625f), GCX - 1);
    const int cys = cell_clamp((int)(py * 0.0625f), GCY - 1);
    const int cxlo = cxs > 0 ? cxs - 1 : 0;
    const int cxhi = cxs < GCX - 1 ? cxs + 1 : GCX - 1;

    const int*    gst = starts + pair * CSTRIDE;
    const float2* gbx = bx + (size_t)pair * NN;

#pragma unroll
    for (int dy = -1; dy <= 1; ++dy) {
        const int cy2 = cys + dy;
        if ((unsigned)cy2 >= (unsigned)GCY) continue;
        const int b0 = gst[cy2 * GCX + cxlo];
        const int e0 = gst[cy2 * GCX + cxhi + 1];
        for (int idx = b0; idx < e0; ++idx) {
            const float2 q = gbx[idx];
            const float ax = px - q.x, ay = py - q.y;
            if (fmaf(ax, ax, ay * ay) <= 64.0f) {        // identical d2 test
                const unsigned int s2 = atomicAdd(&wqc[wave], 1u);
                if (s2 < WQ_CAP) wq[wave][s2] = ((unsigned int)nloc << 11) | (unsigned int)idx;
            }
        }
    }

    // ---- flush wave queue: one global atomic per wave ----
    const unsigned int wn = min(wqc[wave], (unsigned int)WQ_CAP);
    unsigned int wbase = 0u;
    if (lane == 0) wbase = atomicAdd(&hitcnt[pair], wn); // exact count (pre-clamp)
    wbase = (unsigned int)__shfl((int)wbase, 0, 64);
    const int* gbm = bm + (size_t)pair * NN;
    unsigned int* gl = hitlist + (size_t)pair * HCAP;
    for (unsigned int t = lane; t < wn; t += 64) {
        const unsigned int rec = wq[wave][t];
        const int m = gbm[rec & 2047u];                  // resolve original m here
        const unsigned int n = (unsigned int)(tile * 256) + (rec >> 11);
        const unsigned int pos = wbase + t;
        if (pos < HCAP) gl[pos] = (n << 11) | (unsigned int)m;
    }
}

// Kernel 3 (2048 blocks = 4/CU, all co-resident): pure feature gather.
// Block = (pair, chunk of 32 hits), 8 lanes/hit, one pass. pair=bid&15
// keeps each XCD on 2 pairs sharing the src feature batch (L2 locality).
__global__ __launch_bounds__(256, 4) void cos_kernel(const float* __restrict__ feat,
                                                     const unsigned int* __restrict__ hitcnt,
                                                     const unsigned int* __restrict__ hitlist,
                                                     float* __restrict__ psum) {
    __shared__ float bsum[4];
    const int pair  = blockIdx.x & 15;
    const int chunk = blockIdx.x >> 4;                   // 0..127
    const int i = pair >> 2;
    const int j = pair & 3;
    const int wave = threadIdx.x >> 6;
    const int lane = threadIdx.x & 63;

    const unsigned int cnt = min(hitcnt[pair], (unsigned int)HCAP);
    const unsigned int hid = (unsigned int)(chunk * 32 + (threadIdx.x >> 3));
    const int sub = threadIdx.x & 7;
    const bool valid = hid < cnt;

    float dd = 0.0f, aa = 0.0f, bb = 0.0f;
    if (valid) {
        const unsigned int rec = hitlist[(size_t)pair * HCAP + hid];
        const int n = (int)(rec >> 11);
        const int m = (int)(rec & 2047u);
        const float4* pa = (const float4*)(feat + (size_t)(j * NN + n) * DD);
        const float4* pb = (const float4*)(feat + (size_t)(i * NN + m) * DD);
#pragma unroll
        for (int t = 0; t < 8; ++t) {
            const float4 a = pa[t * 8 + sub];
            const float4 b = pb[t * 8 + sub];
            dd = fmaf(a.x, b.x, fmaf(a.y, b.y, fmaf(a.z, b.z, fmaf(a.w, b.w, dd))));
            aa = fmaf(a.x, a.x, fmaf(a.y, a.y, fmaf(a.z, a.z, fmaf(a.w, a.w, aa))));
            bb = fmaf(b.x, b.x, fmaf(b.y, b.y, fmaf(b.z, b.z, fmaf(b.w, b.w, bb))));
        }
    }
    dd += __shfl_xor(dd, 1, 64);  aa += __shfl_xor(aa, 1, 64);  bb += __shfl_xor(bb, 1, 64);
    dd += __shfl_xor(dd, 2, 64);  aa += __shfl_xor(aa, 2, 64);  bb += __shfl_xor(bb, 2, 64);
    dd += __shfl_xor(dd, 4, 64);  aa += __shfl_xor(aa, 4, 64);  bb += __shfl_xor(bb, 4, 64);
    float lsum = 0.0f;
    if (valid && sub == 0) {
        const float p = aa * bb;                         // (|fa|*|fb|)^2 >> eps^2
        float rr = rsqrtf(p);
        rr = rr * (1.5f - 0.5f * p * rr * rr);           // one Newton step
        lsum = 1.0f - dd * rr;
    }
#pragma unroll
    for (int off = 32; off >= 1; off >>= 1) lsum += __shfl_xor(lsum, off, 64);

    if (lane == 0) bsum[wave] = lsum;
    __syncthreads();
    if (threadIdx.x == 0)
        psum[blockIdx.x] = bsum[0] + bsum[1] + bsum[2] + bsum[3];  // 0 if no hits
}

// Kernel 4: reduce 2048 partials + 16 exact counters. One block.
__global__ __launch_bounds__(256) void finalize_kernel(const float* __restrict__ psum,
                                                       const unsigned int* __restrict__ hitcnt,
                                                       float* __restrict__ out) {
    float s = 0.0f;
    float c = 0.0f;                                      // hits < 2^24, exact in f32
    for (int t = threadIdx.x; t < CBLK; t += 256) s += psum[t];
    if (threadIdx.x < NPAIR) c = (float)hitcnt[threadIdx.x];
#pragma unroll
    for (int off = 32; off >= 1; off >>= 1) {
        s += __shfl_xor(s, off, 64);
        c += __shfl_xor(c, off, 64);
    }
    __shared__ float ss[4], cc[4];
    const int wave = threadIdx.x >> 6;
    const int lane = threadIdx.x & 63;
    if (lane == 0) { ss[wave] = s; cc[wave] = c; }
    __syncthreads();
    if (threadIdx.x == 0) {
        const float S = ss[0] + ss[1] + ss[2] + ss[3];
        const float C = cc[0] + cc[1] + cc[2] + cc[3];
        out[0] = S / fmaxf(C, 1.0f);                     // max(cnt, 1)
    }
}

extern "C" void kernel_launch(void* const* d_in, const int* in_sizes, int n_in,
                              void* d_out, int out_size, void* d_ws, size_t ws_size,
                              hipStream_t stream) {
    const float* feat    = (const float*)d_in[0];   // [B,N,D] f32
    const float* pts_src = (const float*)d_in[1];   // [B,N,2] f32
    const float* pts_dst = (const float*)d_in[2];   // [B,B,N,2] f32
    // d_in[3] = invis_idx — unused by the reference
    const int* hptr = (const int*)d_in[4];          // height (scalar)
    const int* wptr = (const int*)d_in[5];          // width  (scalar)
    float* out = (float*)d_out;

    int*          starts  = (int*)d_ws;
    float2*       bx      = (float2*)((char*)d_ws + OFF_BX);
    int*          bm      = (int*)((char*)d_ws + OFF_BM);
    unsigned int* hitcnt  = (unsigned int*)((char*)d_ws + OFF_HC);
    unsigned int* hitlist = (unsigned int*)((char*)d_ws + OFF_HL);
    float*        psum    = (float*)((char*)d_ws + OFF_PS);

    build_kernel<<<NPAIR, 256, 0, stream>>>(pts_dst, hptr, wptr, starts, bx, bm, hitcnt);
    match_kernel<<<MBLK, 256, 0, stream>>>(pts_src, hptr, wptr, starts, bx, bm,
                                           hitcnt, hitlist);
    cos_kernel<<<CBLK, 256, 0, stream>>>(feat, hitcnt, hitlist, psum);
    finalize_kernel<<<1, 256, 0, stream>>>(psum, hitcnt, out);
}